// Round 12
// baseline (661.336 us; speedup 1.0000x reference)
//
#include <hip/hip_runtime.h>
#include <math.h>

#define NN 100000   // nodes
#define INF 128     // input features
#define DD  512     // hidden dim
#define GG  64      // graphs
#define CC  10      // classes

typedef __bf16 bf16;
typedef __bf16 bf16x8 __attribute__((ext_vector_type(8)));
typedef __bf16 bf16x4 __attribute__((ext_vector_type(4)));
typedef float  f32x4  __attribute__((ext_vector_type(4)));
typedef unsigned int u32x4 __attribute__((ext_vector_type(4)));

#define NRB ((NN + 127) / 128)          // 782 row-blocks

// async global->LDS, 16 bytes per lane. LDS dest is wave-uniform base +
// lane*16 (HW-defined); global src is per-lane.
__device__ __forceinline__ void gld16(const bf16* g, bf16* l) {
    __builtin_amdgcn_global_load_lds(
        (const __attribute__((address_space(1))) unsigned int*)g,
        (__attribute__((address_space(3))) unsigned int*)l, 16, 0, 0);
}

// BN fold helpers: s = gamma*rsqrt(var+eps), t = beta - mean*s (biased var)
__device__ __forceinline__ float bn_s(const float* stats, const float* gamma,
                                      int K, int k) {
    const float invN = 1.0f / (float)NN;
    float mean = stats[k] * invN;
    float var  = stats[K + k] * invN - mean * mean;
    return gamma[k] * rsqrtf(var + 1e-5f);
}
__device__ __forceinline__ float bn_t(const float* stats, const float* gamma,
                                      const float* beta, int K, int k) {
    const float invN = 1.0f / (float)NN;
    float mean = stats[k] * invN;
    float var  = stats[K + k] * invN - mean * mean;
    float sv   = gamma[k] * rsqrtf(var + 1e-5f);
    return beta[k] - mean * sv;
}

// ---------------------------------------------------------------------------
// small utility kernels
// ---------------------------------------------------------------------------

__global__ void zero_k(float* __restrict__ p, int n) {
    int i = blockIdx.x * blockDim.x + threadIdx.x;
    if (i < n) p[i] = 0.0f;
}

__global__ void bounds_k(const int* __restrict__ batch, int* __restrict__ starts) {
    int g = threadIdx.x;
    if (g <= GG) {
        int lo = 0, hi = NN;
        while (lo < hi) {
            int mid = (lo + hi) >> 1;
            if (batch[mid] < g) lo = mid + 1; else hi = mid;
        }
        starts[g] = lo;
    }
}

// fused: exact fp32 column stats of x (NN x 128) + bf16 cast, vectorized.
__global__ __launch_bounds__(256)
void colstats_cvt(const float* __restrict__ x, bf16* __restrict__ xb,
                  float* __restrict__ stats) {
    __shared__ float rs[4][128], rq[4][128];
    int t = threadIdx.x;
    int w = t >> 6, l = t & 63;
    int rg = t >> 5;      // 0..7 row-group
    int cq = t & 31;      // col-quad (4 cols)
    float s0 = 0, s1 = 0, s2 = 0, s3 = 0, q0 = 0, q1 = 0, q2 = 0, q3 = 0;
    for (int row = blockIdx.x * 8 + rg; row < NN; row += gridDim.x * 8) {
        float4 v = *(const float4*)&x[(size_t)row * INF + cq * 4];
        bf16x4 o; o[0] = (bf16)v.x; o[1] = (bf16)v.y; o[2] = (bf16)v.z; o[3] = (bf16)v.w;
        *(bf16x4*)&xb[(size_t)row * INF + cq * 4] = o;
        s0 += v.x; q0 += v.x * v.x;
        s1 += v.y; q1 += v.y * v.y;
        s2 += v.z; q2 += v.z * v.z;
        s3 += v.w; q3 += v.w * v.w;
    }
    s0 += __shfl_xor(s0, 32); s1 += __shfl_xor(s1, 32);
    s2 += __shfl_xor(s2, 32); s3 += __shfl_xor(s3, 32);
    q0 += __shfl_xor(q0, 32); q1 += __shfl_xor(q1, 32);
    q2 += __shfl_xor(q2, 32); q3 += __shfl_xor(q3, 32);
    if (l < 32) {
        rs[w][cq * 4 + 0] = s0; rs[w][cq * 4 + 1] = s1;
        rs[w][cq * 4 + 2] = s2; rs[w][cq * 4 + 3] = s3;
        rq[w][cq * 4 + 0] = q0; rq[w][cq * 4 + 1] = q1;
        rq[w][cq * 4 + 2] = q2; rq[w][cq * 4 + 3] = q3;
    }
    __syncthreads();
    if (t < 128) {
        atomicAdd(&stats[t],       rs[0][t] + rs[1][t] + rs[2][t] + rs[3][t]);
        atomicAdd(&stats[INF + t], rq[0][t] + rq[1][t] + rq[2][t] + rq[3][t]);
    }
}

// Wt[j][k] = bf16( s[k] * W[k][j] ) via LDS 64x64 tile transpose.
// s computed inline from stats/gamma (stats==null -> s=1).
__global__ __launch_bounds__(256)
void fold_wt(const float* __restrict__ stats, const float* __restrict__ gamma,
             const float* __restrict__ W, bf16* __restrict__ Wt, int K) {
    __shared__ float tile[64][68];
    __shared__ float sarr[64];
    int j0 = blockIdx.x * 64, k0 = blockIdx.y * 64;
    int t = threadIdx.x;
    if (t < 64) sarr[t] = stats ? bn_s(stats, gamma, K, k0 + t) : 1.0f;
    int kk = t >> 2, jq = t & 3;
#pragma unroll
    for (int i = 0; i < 4; i++) {
        float4 v = *(const float4*)&W[(size_t)(k0 + kk) * DD + j0 + jq * 16 + i * 4];
        *(float4*)&tile[kk][jq * 16 + i * 4] = v;
    }
    __syncthreads();
    int jj = t >> 2, kq = t & 3;
    bf16 ov[16];
#pragma unroll
    for (int i = 0; i < 16; i++)
        ov[i] = (bf16)(tile[kq * 16 + i][jj] * sarr[kq * 16 + i]);
    bf16* dst = &Wt[(size_t)(j0 + jj) * K + k0 + kq * 16];
    *(u32x4*)dst       = *(u32x4*)&ov[0];
    *(u32x4*)(dst + 8) = *(u32x4*)&ov[8];
}

// bp[j] = b[j] + sum_k t[k]*W[k][j]; t computed inline. grid 8, block 256.
__global__ __launch_bounds__(256)
void fold_b(const float* __restrict__ stats, const float* __restrict__ gamma,
            const float* __restrict__ beta, const float* __restrict__ W,
            const float* __restrict__ b, float* __restrict__ bp, int K) {
    __shared__ float red[4][64];
    __shared__ float tt[DD];
    int t = threadIdx.x;
    for (int k = t; k < K; k += 256) tt[k] = bn_t(stats, gamma, beta, K, k);
    __syncthreads();
    int jj = t & 63, kr = t >> 6;
    int j = blockIdx.x * 64 + jj;
    float acc = 0.f;
    for (int k = kr; k < K; k += 4)
        acc += tt[k] * W[(size_t)k * DD + j];
    red[kr][jj] = acc;
    __syncthreads();
    if (kr == 0) bp[j] = b[j] + red[0][jj] + red[1][jj] + red[2][jj] + red[3][jj];
}

// ---------------------------------------------------------------------------
// MFMA GEMM: global_load_lds staging + XOR slot swizzle + DOUBLE-BUFFERED LDS
// 2-phase pipeline (issue next-tile loads BEFORE computing current tile; the
// compiler's vmcnt(0)-before-barrier then lands AFTER compute, so HBM latency
// hides under ds_read+MFMA).
// A: M x K bf16, Wt: 512 x K bf16 (pre-T). grid (4, NRB) — r10 mapping
// (XCD banding reverted: measured -43% in r11, lock-step L2 sharing exposed
// full HBM latency every k-step).
// LDS: 2 buffers x (As 16KB | Bs 16KB) = 64KB -> 2 blocks/CU.
// Slot permutation (slot ^ (row&7)) on BOTH global source and ds_read ->
// conflict-free (verified r10: 0 conflicts).
// MODE 0: plain store. MODE 1: + fused column sum/sumsq.
// MODE 2: stats + segment-pool into R, NO H store.
// MODE 0/1 store via LDS C-tile (stride 136) -> fully-coalesced 16B stores.
// ---------------------------------------------------------------------------
template <int K, int MODE>
__global__ __launch_bounds__(256, 2)
void gemm_mfma(const bf16* __restrict__ A, const bf16* __restrict__ Wt,
               const float* __restrict__ bias, bf16* __restrict__ H, int M,
               float* __restrict__ stats, const int* __restrict__ batch,
               float* __restrict__ R) {
    __shared__ bf16 smem[32768];                 // 64KB: buf{0,1} x (As|Bs)
    const int t  = threadIdx.x;
    const int l  = t & 63;
    const int w  = t >> 6;
    const int wr = w >> 1, wc = w & 1;
    const int col0 = blockIdx.x * 128;           // x fastest = col block
    const int row0 = blockIdx.y * 128;

    // staging geometry: thread covers rows c*32 + w*8 + (l>>3), slot l&7
    const int srow = w * 8 + (l >> 3);
    const int sslt = l & 7;

    f32x4 acc[4][4];
#pragma unroll
    for (int m = 0; m < 4; m++)
#pragma unroll
        for (int n = 0; n < 4; n++) acc[m][n] = (f32x4){0.f, 0.f, 0.f, 0.f};

    // stage one 128x64 A-tile + B-tile into buffer b
    auto stage = [&](int b, int k0) {
        bf16* As = smem + b * 16384;
        bf16* Bs = As + 8192;
#pragma unroll
        for (int c = 0; c < 4; c++) {
            int r  = c * 32 + srow;              // LDS row 0..127
            int sg = sslt ^ (r & 7);             // pre-swizzled source slot
            int ga = row0 + r; if (ga >= M) ga = M - 1;
            gld16(A  + (size_t)ga * K + k0 + sg * 8,
                  (bf16*)((char*)As + c * 4096 + w * 1024));
            gld16(Wt + (size_t)(col0 + r) * K + k0 + sg * 8,
                  (bf16*)((char*)Bs + c * 4096 + w * 1024));
        }
    };

    // MFMA over buffer b (ds_read with matching XOR swizzle)
    auto compute = [&](int b) {
        const bf16* As = smem + b * 16384;
        const bf16* Bs = As + 8192;
#pragma unroll
        for (int ks = 0; ks < 2; ks++) {
            bf16x8 af[4], bfr[4];
#pragma unroll
            for (int m = 0; m < 4; m++) {
                int r = wr * 64 + m * 16 + (l & 15);
                af[m] = *(const bf16x8*)((const char*)As + r * 128 +
                        ((((ks << 2) + (l >> 4)) ^ (r & 7)) << 4));
            }
#pragma unroll
            for (int n = 0; n < 4; n++) {
                int r = wc * 64 + n * 16 + (l & 15);
                bfr[n] = *(const bf16x8*)((const char*)Bs + r * 128 +
                         ((((ks << 2) + (l >> 4)) ^ (r & 7)) << 4));
            }
#pragma unroll
            for (int m = 0; m < 4; m++)
#pragma unroll
                for (int n = 0; n < 4; n++)
                    acc[m][n] = __builtin_amdgcn_mfma_f32_16x16x32_bf16(af[m], bfr[n], acc[m][n], 0, 0, 0);
        }
    };

    // 2-phase pipeline: prologue stage, then {stage(next) || compute(cur)}
    int cur = 0;
    stage(0, 0);
    __syncthreads();                             // vmcnt(0): buf0 ready
#pragma unroll 1
    for (int k0 = 64; k0 < K; k0 += 64) {
        stage(cur ^ 1, k0);                      // loads fly during compute
        compute(cur);
        __syncthreads();                         // drains vmcnt: next buf ready
        cur ^= 1;
    }
    compute(cur);
    __syncthreads();                             // all LDS reads done (smem reuse)

    float csumA[4], csqA[4];

    if (MODE <= 1) {
        // bias+relu -> C-tile in LDS (stride 136 bf16 = 272B), stats in regs
        bf16* ct = smem;
#pragma unroll
        for (int n = 0; n < 4; n++) {
            int lc = wc * 64 + n * 16 + (l & 15);
            float bv = bias[col0 + lc];
            float cs = 0.f, cq = 0.f;
#pragma unroll
            for (int m = 0; m < 4; m++) {
#pragma unroll
                for (int q = 0; q < 4; q++) {
                    int lr = wr * 64 + m * 16 + (l >> 4) * 4 + q;
                    float v = acc[m][n][q] + bv;
                    v = v > 0.f ? v : 0.f;
                    ct[lr * 136 + lc] = (bf16)v;
                    if (MODE == 1 && row0 + lr < M) { cs += v; cq += v * v; }
                }
            }
            csumA[n] = cs; csqA[n] = cq;
        }
        __syncthreads();
        // coalesced store: 8 iters x 256 threads x 16B = 32KB tile
        {
            const char* cts = (const char*)ct;
            char* Hc = (char*)H;
#pragma unroll
            for (int i = 0; i < 8; i++) {
                int fo = i * 4096 + t * 16;
                int r  = fo >> 8;          // tile row (256B of payload per row)
                int cb = fo & 255;
                if (row0 + r < M)
                    *(u32x4*)(Hc + ((size_t)(row0 + r) * (DD * 2) + (size_t)col0 * 2 + cb)) =
                        *(const u32x4*)(cts + r * 272 + cb);
            }
        }
    } else {
        // MODE 2: stats + segment-pool straight from registers; no H store.
        int gid[4][4];
#pragma unroll
        for (int m = 0; m < 4; m++)
#pragma unroll
            for (int q = 0; q < 4; q++) {
                int grow = row0 + wr * 64 + m * 16 + (l >> 4) * 4 + q;
                gid[m][q] = (grow < M) ? batch[grow] : -1;
            }
#pragma unroll
        for (int n = 0; n < 4; n++) {
            int col = col0 + wc * 64 + n * 16 + (l & 15);
            float bv = bias[col];
            float cs = 0.f, cq = 0.f;
            float ps = 0.f; int gc = -1;
#pragma unroll
            for (int m = 0; m < 4; m++) {
#pragma unroll
                for (int q = 0; q < 4; q++) {
                    int g = gid[m][q];
                    if (g >= 0) {
                        float v = acc[m][n][q] + bv;
                        v = v > 0.f ? v : 0.f;
                        cs += v; cq += v * v;
                        if (g != gc) {
                            if (gc >= 0) atomicAdd(&R[(size_t)gc * DD + col], ps);
                            ps = 0.f; gc = g;
                        }
                        ps += v;
                    }
                }
            }
            if (gc >= 0) atomicAdd(&R[(size_t)gc * DD + col], ps);
            csumA[n] = cs; csqA[n] = cq;
        }
    }

    if (MODE >= 1) {
#pragma unroll
        for (int n = 0; n < 4; n++) {
            float cs = csumA[n], cq = csqA[n];
            cs += __shfl_xor(cs, 16); cs += __shfl_xor(cs, 32);
            cq += __shfl_xor(cq, 16); cq += __shfl_xor(cq, 32);
            if ((l >> 4) == 0) {
                int col = col0 + wc * 64 + n * 16 + l;
                atomicAdd(&stats[col], cs);
                atomicAdd(&stats[DD + col], cq);
            }
        }
    }
}

// P[g][j] = R[g][j]*s4[j] + cnt_g*t4[j]; s4/t4 computed inline from stats4.
__global__ __launch_bounds__(512)
void pool_fin(const float* __restrict__ R, const int* __restrict__ starts,
              const float* __restrict__ stats, const float* __restrict__ gamma,
              const float* __restrict__ beta, float* __restrict__ P) {
    int g = blockIdx.x, j = threadIdx.x;
    float sv = bn_s(stats, gamma, DD, j);
    float tv = bn_t(stats, gamma, beta, DD, j);
    float cnt = (float)(starts[g + 1] - starts[g]);
    P[g * DD + j] = R[(size_t)g * DD + j] * sv + cnt * tv;
}

// ---------------------------------------------------------------------------
// head: per-graph  prelu(P@fc1+b) -> sigmoid(@fc2+b) -> @fc3+b  (fp32)
// ---------------------------------------------------------------------------
__global__ __launch_bounds__(256)
void head_k(const float* __restrict__ P,
            const float* __restrict__ fc1_w, const float* __restrict__ fc1_b,
            const float* __restrict__ fc2_w, const float* __restrict__ fc2_b,
            const float* __restrict__ fc3_w, const float* __restrict__ fc3_b,
            const float* __restrict__ a3, float* __restrict__ out) {
    __shared__ float p[DD], y1[DD], y2[DD / 2];
    int g = blockIdx.x, t = threadIdx.x;
    p[t]       = P[g * DD + t];
    p[t + 256] = P[g * DD + t + 256];
    __syncthreads();
    float alpha = a3[0];

    float acc0 = fc1_b[t], acc1 = fc1_b[t + 256];
    for (int k = 0; k < DD; k++) {
        float pv = p[k];
        acc0 = fmaf(pv, fc1_w[(size_t)k * DD + t], acc0);
        acc1 = fmaf(pv, fc1_w[(size_t)k * DD + t + 256], acc1);
    }
    y1[t]       = acc0 >= 0.f ? acc0 : alpha * acc0;
    y1[t + 256] = acc1 >= 0.f ? acc1 : alpha * acc1;
    __syncthreads();

    float acc = fc2_b[t];
    for (int k = 0; k < DD; k++) acc = fmaf(y1[k], fc2_w[(size_t)k * (DD / 2) + t], acc);
    y2[t] = 1.0f / (1.0f + expf(-acc));
    __syncthreads();

    if (t < CC) {
        float a = fc3_b[t];
        for (int k = 0; k < DD / 2; k++) a = fmaf(y2[k], fc3_w[(size_t)k * CC + t], a);
        out[g * CC + t] = a;
    }
}

// ---------------------------------------------------------------------------
// launch
// ---------------------------------------------------------------------------
extern "C" void kernel_launch(void* const* d_in, const int* in_sizes, int n_in,
                              void* d_out, int out_size, void* d_ws, size_t ws_size,
                              hipStream_t stream) {
    const float* x     = (const float*)d_in[0];
    /* d_in[1] edge_index: unused (ChebConv K=1 == linear) */
    const int*   batch = (const int*)d_in[2];
    const float* bn1_g = (const float*)d_in[3];
    const float* bn1_b = (const float*)d_in[4];
    const float* w0    = (const float*)d_in[5];
    const float* b0    = (const float*)d_in[6];
    const float* w1    = (const float*)d_in[7];
    const float* bb1   = (const float*)d_in[8];
    const float* w2    = (const float*)d_in[9];
    const float* bb2   = (const float*)d_in[10];
    const float* w3    = (const float*)d_in[11];
    const float* bb3   = (const float*)d_in[12];
    const float* bn3_g = (const float*)d_in[13];
    const float* bn3_b = (const float*)d_in[14];
    const float* a3    = (const float*)d_in[15];
    const float* fc1_w = (const float*)d_in[16];
    const float* fc1_b = (const float*)d_in[17];
    const float* fc2_w = (const float*)d_in[18];
    const float* fc2_b = (const float*)d_in[19];
    const float* fc3_w = (const float*)d_in[20];
    const float* fc3_b = (const float*)d_in[21];
    float* out = (float*)d_out;

    // ---- workspace layout ----
    char* base = (char*)d_ws;
    const size_t HBYTES = (size_t)NN * DD * 2;       // 102,400,000
    bf16* Ha = (bf16*)base;
    bf16* Hb = (bf16*)(base + HBYTES);
    bf16* Xb = Hb;                                   // alias: dead after layer0
    bf16* Wt = (bf16*)(base + 2 * HBYTES);           // 512*512*2 = 524,288
    float* f = (float*)(base + 2 * HBYTES + 524288);
    size_t off = 0;
    float* stats  = f + off; off += 3328;            // x(256) + 3 layers (1024 each)
    float* R      = f + off; off += (size_t)GG * DD; // 32,768 (zeroed with stats)
    float* statsX = stats;
    float* stats2 = stats + 256;
    float* stats3 = stats + 1280;
    float* stats4 = stats + 2304;
    float* b0p = f + off; off += 512;
    float* bp  = f + off; off += 512;
    float* P   = f + off; off += (size_t)GG * DD;    // 32,768
    int*   starts = (int*)(f + off); off += 128;

    (void)in_sizes; (void)n_in; (void)out_size; (void)ws_size;

    const dim3 ggrid(4, NRB);                        // r10 mapping (reverted)
    const int kZeroCount = 3328 + GG * DD;           // stats + R contiguous

    zero_k<<<(kZeroCount + 255) / 256, 256, 0, stream>>>(stats, kZeroCount);
    bounds_k<<<1, 128, 0, stream>>>(batch, starts);

    // BN1 (exact fp32 stats on x) fused with bf16 cast; fold into layer0
    colstats_cvt<<<256, 256, 0, stream>>>(x, Xb, statsX);
    fold_wt<<<dim3(8, INF / 64), 256, 0, stream>>>(statsX, bn1_g, w0, Wt, INF);
    fold_b<<<8, 256, 0, stream>>>(statsX, bn1_g, bn1_b, w0, b0, b0p, INF);
    // layer0: Ha = relu(Xb @ W0' + b0')
    gemm_mfma<INF, 0><<<ggrid, 256, 0, stream>>>(Xb, Wt, b0p, Ha, NN, nullptr, nullptr, nullptr);

    // layer1: Hb = relu(Ha @ w1 + bb1) + fused stats2
    fold_wt<<<dim3(8, DD / 64), 256, 0, stream>>>(nullptr, nullptr, w1, Wt, DD);
    gemm_mfma<DD, 1><<<ggrid, 256, 0, stream>>>(Ha, Wt, bb1, Hb, NN, stats2, nullptr, nullptr);

    // layer2: fold BN(stats2) into w2; Ha = relu(Hb @ W2' + b2') + stats3
    fold_wt<<<dim3(8, DD / 64), 256, 0, stream>>>(stats2, bn3_g, w2, Wt, DD);
    fold_b<<<8, 256, 0, stream>>>(stats2, bn3_g, bn3_b, w2, bb2, bp, DD);
    gemm_mfma<DD, 1><<<ggrid, 256, 0, stream>>>(Hb, Wt, bp, Ha, NN, stats3, nullptr, nullptr);

    // layer3: fold BN(stats3) into w3; stats4 + segment-pool fused, no H store
    fold_wt<<<dim3(8, DD / 64), 256, 0, stream>>>(stats3, bn3_g, w3, Wt, DD);
    fold_b<<<8, 256, 0, stream>>>(stats3, bn3_g, bn3_b, w3, bb3, bp, DD);
    gemm_mfma<DD, 2><<<ggrid, 256, 0, stream>>>(Ha, Wt, bp, nullptr, NN, stats4, batch, R);

    // final BN folded into pooled sums (s4/t4 inline)
    pool_fin<<<GG, 512, 0, stream>>>(R, starts, stats4, bn3_g, bn3_b, P);
    head_k<<<GG, 256, 0, stream>>>(P, fc1_w, fc1_b, fc2_w, fc2_b, fc3_w, fc3_b, a3, out);
}